// Round 14
// baseline (3181.376 us; speedup 1.0000x reference)
//
#include <hip/hip_runtime.h>
#include <math.h>

#define NB 4
#define CC 128
#define HW 784        // 28*28
#define KK 64
#define DD 512
#define TD 8          // d-rows per block
#define CH 64         // channels per c-half
#define NPAIR 392     // pixel pairs (784/2)
#define HTH 416       // threads per c-half (392 active + pad)
#define BLK 832       // 13 waves
#define REP 16        // GEMM-phase amplification for measurement

// MEASUREMENT ROUND (R11 base, best=17.0us): the GEMM phase repeats REP=16x
// with a memory-clobber between reps (defeats load CSE), accumulators scaled
// by exactly 1/16 at the end (pow2 -> bit-exact scaling; reorder error ~ulp).
// Purpose: (a) GEMM phase duration = (T - 17.0)/15; (b) kernel dispatch
// becomes the largest in the profile -> first-ever full counter row
// (VALUBusy / FETCH_SIZE / SQ_LDS_BANK_CONFLICT / Occupancy) for this kernel.
__global__ __launch_bounds__(BLK) void netvlad_fused_kernel(
    const float* __restrict__ x, const float* __restrict__ w,
    const float* __restrict__ b, float* __restrict__ out)
{
    __shared__ float w_s[CC][TD];        // 4 KB, transposed [c][j]
    __shared__ float feat_s[TD][HW];     // 25 KB
    __shared__ float sq_s[HW];           // 3.1 KB
    __shared__ float g_s[TD];

    const int tid = threadIdx.x;
    const int n  = blockIdx.x >> 6;
    const int d0 = (blockIdx.x & 63) * TD;

    for (int i = tid; i < CC * TD; i += BLK) {
        int c = i >> 3, j = i & 7;
        w_s[c][j] = w[(size_t)(d0 + j) * CC + c];
    }

    const int  ch  = (tid >= HTH) ? 1 : 0;
    const int  qr  = tid - ch * HTH;      // 0..415
    const bool act = qr < NPAIR;
    const int  q   = act ? qr : (NPAIR - 1);
    const int  p   = 2 * q;
    const int  cb  = ch * CH;

    __syncthreads();

    const float* xp = x + (size_t)n * CC * HW + (size_t)cb * HW + p;

    float acc0[TD], acc1[TD];
    #pragma unroll
    for (int j = 0; j < TD; ++j) { acc0[j] = 0.f; acc1[j] = 0.f; }
    float sq0 = 0.f, sq1 = 0.f;

    for (int rep = 0; rep < REP; ++rep) {
        asm volatile("" ::: "memory");   // force re-execution of loads each rep
        for (int cc = 0; cc < CH; cc += 8) {
            float2 xv[8];
            #pragma unroll
            for (int u = 0; u < 8; ++u)
                xv[u] = *(const float2*)&xp[(size_t)(cc + u) * HW];
            #pragma unroll
            for (int u = 0; u < 8; ++u) {
                const int c = cb + cc + u;
                float4 wlo = *(const float4*)&w_s[c][0];
                float4 whi = *(const float4*)&w_s[c][4];
                float a = xv[u].x, e = xv[u].y;
                sq0 = fmaf(a, a, sq0);
                sq1 = fmaf(e, e, sq1);
                acc0[0] = fmaf(wlo.x, a, acc0[0]);  acc1[0] = fmaf(wlo.x, e, acc1[0]);
                acc0[1] = fmaf(wlo.y, a, acc0[1]);  acc1[1] = fmaf(wlo.y, e, acc1[1]);
                acc0[2] = fmaf(wlo.z, a, acc0[2]);  acc1[2] = fmaf(wlo.z, e, acc1[2]);
                acc0[3] = fmaf(wlo.w, a, acc0[3]);  acc1[3] = fmaf(wlo.w, e, acc1[3]);
                acc0[4] = fmaf(whi.x, a, acc0[4]);  acc1[4] = fmaf(whi.x, e, acc1[4]);
                acc0[5] = fmaf(whi.y, a, acc0[5]);  acc1[5] = fmaf(whi.y, e, acc1[5]);
                acc0[6] = fmaf(whi.z, a, acc0[6]);  acc1[6] = fmaf(whi.z, e, acc1[6]);
                acc0[7] = fmaf(whi.w, a, acc0[7]);  acc1[7] = fmaf(whi.w, e, acc1[7]);
            }
        }
    }

    // exact 1/REP scaling (power of two)
    const float inv = 1.0f / (float)REP;
    sq0 *= inv;  sq1 *= inv;
    #pragma unroll
    for (int j = 0; j < TD; ++j) { acc0[j] *= inv; acc1[j] *= inv; }

    if (act && ch == 0) {
        sq_s[p] = sq0;  sq_s[p + 1] = sq1;
        #pragma unroll
        for (int j = 0; j < TD; ++j) {
            feat_s[j][p]     = acc0[j];
            feat_s[j][p + 1] = acc1[j];
        }
    }
    __syncthreads();
    if (act && ch == 1) {
        float r0 = 1.0f / fmaxf(sqrtf(sq_s[p] + sq0), 1e-12f);
        float r1 = 1.0f / fmaxf(sqrtf(sq_s[p + 1] + sq1), 1e-12f);
        #pragma unroll
        for (int j = 0; j < TD; ++j) {
            float bj = b[d0 + j];
            feat_s[j][p]     = fmaf(feat_s[j][p]     + acc0[j], r0, bj);
            feat_s[j][p + 1] = fmaf(feat_s[j][p + 1] + acc1[j], r1, bj);
        }
    }
    __syncthreads();

    const int lane = tid & 63;
    const int wave = tid >> 6;
    if (wave < TD) {
        const int j = wave;
        float m = -INFINITY;
        for (int u = lane; u < HW; u += 64) m = fmaxf(m, feat_s[j][u]);
        #pragma unroll
        for (int off = 32; off; off >>= 1) m = fmaxf(m, __shfl_xor(m, off, 64));
        float s = 0.f, ws = 0.f;
        for (int u = lane; u < HW; u += 64) {
            float f = feat_s[j][u];
            float e = __expf(f - m);
            s += e;
            ws = fmaf(e, f, ws);
        }
        #pragma unroll
        for (int off = 32; off; off >>= 1) {
            s  += __shfl_xor(s, off, 64);
            ws += __shfl_xor(ws, off, 64);
        }
        if (lane == 0) g_s[j] = ws / s;
    }
    __syncthreads();

    if (tid < KK * TD) {
        int k = tid >> 3, j = tid & 7;
        out[(size_t)n * KK * DD + (size_t)k * DD + d0 + j] = g_s[j];
    }
}

extern "C" void kernel_launch(void* const* d_in, const int* in_sizes, int n_in,
                              void* d_out, int out_size, void* d_ws, size_t ws_size,
                              hipStream_t stream) {
    const float* x = (const float*)d_in[0];   // (4,128,28,28)
    const float* w = (const float*)d_in[1];   // (512,128)
    const float* b = (const float*)d_in[2];   // (512,)
    // d_in[3] = centroids: unused (softmax shift-invariance over spatial axis)
    float* out = (float*)d_out;               // (4,64,512) fp32

    netvlad_fused_kernel<<<NB * (DD / TD), BLK, 0, stream>>>(x, w, b, out);
}

// Round 15
// 822.612 us; speedup vs baseline: 3.8674x; 3.8674x over previous
//
#include <hip/hip_runtime.h>
#include <math.h>

#define NB 4
#define CC 128
#define HW 784        // 28*28
#define KK 64
#define DD 512
#define TD 8          // d-rows per block
#define CH 64         // channels per rep-window
#define NPAIR 392     // pixel pairs (784/2)
#define HTH 416       // threads per c-half (392 active + pad)
#define BLK 832       // 13 waves
#define REP 8         // GEMM-phase amplification
#define ROT 16        // channel-window rotation per rep

// MEASUREMENT ROUND v2 (R11 base, best=17.0us). GEMM phase x8 via rotated
// 64-channel windows (each channel counted exactly 4x -> scale by exact
// 0.25f). Cross-rep CSE defeated by an ADDRESS-ONLY register clobber
// (R14's "memory" clobber caused scratch spill: VGPR=64, 6.6GB writes).
// Non-writing threads kept live via asm value sink (rule #17).
// Read: G=(T-17)/7 = warm GEMM-phase duration; kernel counter row finally
// outranks the 39us fillBuffer rows -> VALUBusy/FETCH/conflicts readable.
__global__ __launch_bounds__(BLK) void netvlad_probe_kernel(
    const float* __restrict__ x, const float* __restrict__ w,
    const float* __restrict__ b, float* __restrict__ out)
{
    __shared__ float w_s[CC][TD];        // 4 KB, transposed [c][j]
    __shared__ float feat_s[TD][HW];     // 25 KB
    __shared__ float g_s[TD];

    const int tid = threadIdx.x;
    const int n  = blockIdx.x >> 6;
    const int d0 = (blockIdx.x & 63) * TD;

    for (int i = tid; i < CC * TD; i += BLK) {
        int c = i >> 3, j = i & 7;
        w_s[c][j] = w[(size_t)(d0 + j) * CC + c];
    }

    const int  ch  = (tid >= HTH) ? 1 : 0;
    const int  qr  = tid - ch * HTH;      // 0..415
    const bool act = qr < NPAIR;
    const int  q   = act ? qr : (NPAIR - 1);
    const int  p   = 2 * q;
    const int  cb  = ch * CH;

    __syncthreads();

    const float* xn = x + (size_t)n * CC * HW + p;   // pixel-pair base

    float acc0[TD], acc1[TD];
    #pragma unroll
    for (int j = 0; j < TD; ++j) { acc0[j] = 0.f; acc1[j] = 0.f; }
    float sq0 = 0.f, sq1 = 0.f;

    #pragma unroll 1
    for (int rep = 0; rep < REP; ++rep) {
        int coff = cb + rep * ROT;
        asm volatile("" : "+v"(coff));   // opaque base: kills cross-rep CSE only
        for (int cc = 0; cc < CH; cc += 8) {
            int   cidx[8];
            float2 xv[8];
            #pragma unroll
            for (int u = 0; u < 8; ++u) {
                cidx[u] = (coff + cc + u) & (CC - 1);
                xv[u] = *(const float2*)&xn[(size_t)cidx[u] * HW];
            }
            #pragma unroll
            for (int u = 0; u < 8; ++u) {
                const int c = cidx[u];
                float4 wlo = *(const float4*)&w_s[c][0];   // bcast ds_read_b128
                float4 whi = *(const float4*)&w_s[c][4];
                float a = xv[u].x, e = xv[u].y;
                sq0 = fmaf(a, a, sq0);
                sq1 = fmaf(e, e, sq1);
                acc0[0] = fmaf(wlo.x, a, acc0[0]);  acc1[0] = fmaf(wlo.x, e, acc1[0]);
                acc0[1] = fmaf(wlo.y, a, acc0[1]);  acc1[1] = fmaf(wlo.y, e, acc1[1]);
                acc0[2] = fmaf(wlo.z, a, acc0[2]);  acc1[2] = fmaf(wlo.z, e, acc1[2]);
                acc0[3] = fmaf(wlo.w, a, acc0[3]);  acc1[3] = fmaf(wlo.w, e, acc1[3]);
                acc0[4] = fmaf(whi.x, a, acc0[4]);  acc1[4] = fmaf(whi.x, e, acc1[4]);
                acc0[5] = fmaf(whi.y, a, acc0[5]);  acc1[5] = fmaf(whi.y, e, acc1[5]);
                acc0[6] = fmaf(whi.z, a, acc0[6]);  acc1[6] = fmaf(whi.z, e, acc1[6]);
                acc0[7] = fmaf(whi.w, a, acc0[7]);  acc1[7] = fmaf(whi.w, e, acc1[7]);
            }
        }
    }

    // Each channel covered REP*CH/CC = 4x -> exact pow2 scale.
    const float inv = 0.25f;

    if (act && ch == 0) {
        // full dot (all 128 channels) now lives in each ch=0 thread
        float r0 = 1.0f / fmaxf(sqrtf(sq0 * inv), 1e-12f);
        float r1 = 1.0f / fmaxf(sqrtf(sq1 * inv), 1e-12f);
        #pragma unroll
        for (int j = 0; j < TD; ++j) {
            float bj = b[d0 + j];
            feat_s[j][p]     = fmaf(acc0[j] * inv, r0, bj);
            feat_s[j][p + 1] = fmaf(acc1[j] * inv, r1, bj);
        }
    } else {
        // redundant threads: fold + asm sink keeps their work live (no DCE)
        float z = sq0 + sq1;
        #pragma unroll
        for (int j = 0; j < TD; ++j) z += acc0[j] + acc1[j];
        asm volatile("" :: "v"(z));
    }
    __syncthreads();

    // Per-row softmax-weighted mean over P=784; wave j (j<8) handles row j.
    const int lane = tid & 63;
    const int wave = tid >> 6;
    if (wave < TD) {
        const int j = wave;
        float m = -INFINITY;
        for (int u = lane; u < HW; u += 64) m = fmaxf(m, feat_s[j][u]);
        #pragma unroll
        for (int off = 32; off; off >>= 1) m = fmaxf(m, __shfl_xor(m, off, 64));
        float s = 0.f, ws = 0.f;
        for (int u = lane; u < HW; u += 64) {
            float f = feat_s[j][u];
            float e = __expf(f - m);
            s += e;
            ws = fmaf(e, f, ws);
        }
        #pragma unroll
        for (int off = 32; off; off >>= 1) {
            s  += __shfl_xor(s, off, 64);
            ws += __shfl_xor(ws, off, 64);
        }
        if (lane == 0) g_s[j] = ws / s;
    }
    __syncthreads();

    if (tid < KK * TD) {
        int k = tid >> 3, j = tid & 7;
        out[(size_t)n * KK * DD + (size_t)k * DD + d0 + j] = g_s[j];
    }
}

extern "C" void kernel_launch(void* const* d_in, const int* in_sizes, int n_in,
                              void* d_out, int out_size, void* d_ws, size_t ws_size,
                              hipStream_t stream) {
    const float* x = (const float*)d_in[0];   // (4,128,28,28)
    const float* w = (const float*)d_in[1];   // (512,128)
    const float* b = (const float*)d_in[2];   // (512,)
    // d_in[3] = centroids: unused (softmax shift-invariance over spatial axis)
    float* out = (float*)d_out;               // (4,64,512) fp32

    netvlad_probe_kernel<<<NB * (DD / TD), BLK, 0, stream>>>(x, w, b, out);
}

// Round 16
// 22.979 us; speedup vs baseline: 138.4494x; 35.7990x over previous
//
#include <hip/hip_runtime.h>
#include <math.h>

#define NB 4
#define CC 128
#define HW 784        // 28*28
#define KK 64
#define DD 512
#define TD 8          // d-rows per block
#define SLICES 8      // pixel slices per (n, d-group)
#define SPX 98        // pixels per slice (784/8)
#define BLK 128       // 2 waves per block

// K1: block = (n, 8-d-group, 98-pixel slice). Grid = 4*64*8 = 2048 small
// INDEPENDENT blocks (8 blocks/CU, 16 waves/CU, 4/SIMD) instead of one
// 13-wave barrier-locked 832-thread workgroup — every prior variant (R4-R13,
// all 17-19.5us) shared that block shape; this isolates workgroup-grain
// effects at IDENTICAL x traffic (103 MB), VMEM count, and FMA count.
//   - thread t owns pixel p = sl*98 + t (t<98): streams x[n,:,p] over all
//     128 channels (16-deep load batches), 8 conv dots + sumsq in one pass
//   - weights staged transposed in LDS (4 KB), 2 broadcast ds_read_b128/c
//   - feat stays in REGISTERS; partial softmax (no max pass: |feat|<=~0.8,
//     shift-invariance makes partials exact — R8-verified) reduced via
//     wave shuffles + 1 tiny LDS combine; block emits (s,ws) per d-row.
__global__ __launch_bounds__(BLK) void netvlad_gemm_partial(
    const float* __restrict__ x, const float* __restrict__ w,
    const float* __restrict__ b, float2* __restrict__ pws)
{
    __shared__ float w_s[CC][TD];          // 4 KB transposed [c][j]
    __shared__ float2 red_s[2][TD];        // 2-wave combine, 128 B

    const int tid = threadIdx.x;
    const int bid = blockIdx.x;
    const int n   = bid >> 9;              // 512 blocks per n
    const int dg  = (bid >> 3) & 63;
    const int sl  = bid & 7;
    const int d0  = dg * TD;
    const int p0  = sl * SPX;

    // stage the 8x128 weight tile transposed (one-time, 4 KB)
    for (int i = tid; i < CC * TD; i += BLK) {
        int c = i >> 3, j = i & 7;
        w_s[c][j] = w[(size_t)(d0 + j) * CC + c];
    }
    __syncthreads();

    const bool act = tid < SPX;
    const int  p   = p0 + (act ? tid : (SPX - 1));   // clamp keeps loads legal
    const float* xp = x + (size_t)n * CC * HW + p;

    float acc[TD];
    #pragma unroll
    for (int j = 0; j < TD; ++j) acc[j] = 0.f;
    float sq = 0.f;

    // 16-deep load batches over all 128 channels
    for (int cc = 0; cc < CC; cc += 16) {
        float xv[16];
        #pragma unroll
        for (int u = 0; u < 16; ++u)
            xv[u] = xp[(size_t)(cc + u) * HW];       // coalesced dword
        #pragma unroll
        for (int u = 0; u < 16; ++u) {
            const int c = cc + u;
            float4 wlo = *(const float4*)&w_s[c][0]; // uniform -> broadcast
            float4 whi = *(const float4*)&w_s[c][4];
            float xvu = xv[u];
            sq = fmaf(xvu, xvu, sq);
            acc[0] = fmaf(wlo.x, xvu, acc[0]);
            acc[1] = fmaf(wlo.y, xvu, acc[1]);
            acc[2] = fmaf(wlo.z, xvu, acc[2]);
            acc[3] = fmaf(wlo.w, xvu, acc[3]);
            acc[4] = fmaf(whi.x, xvu, acc[4]);
            acc[5] = fmaf(whi.y, xvu, acc[5]);
            acc[6] = fmaf(whi.z, xvu, acc[6]);
            acc[7] = fmaf(whi.w, xvu, acc[7]);
        }
    }

    // feat in registers -> per-thread softmax contributions (0 if inactive)
    const float r = 1.0f / fmaxf(sqrtf(sq), 1e-12f);
    float se[TD], we[TD];
    #pragma unroll
    for (int j = 0; j < TD; ++j) {
        float f = fmaf(acc[j], r, b[d0 + j]);
        float e = act ? __expf(f) : 0.f;
        se[j] = e;
        we[j] = act ? e * f : 0.f;
    }

    // wave-level reduce (6 shuffle steps) for all 8 rows, then 2-wave combine
    #pragma unroll
    for (int j = 0; j < TD; ++j) {
        #pragma unroll
        for (int off = 32; off; off >>= 1) {
            se[j] += __shfl_xor(se[j], off, 64);
            we[j] += __shfl_xor(we[j], off, 64);
        }
    }
    const int lane = tid & 63;
    const int wv   = tid >> 6;
    if (lane < TD) red_s[wv][lane] = make_float2(se[lane], we[lane]);
    __syncthreads();
    if (tid < TD) {
        float2 a = red_s[0][tid], c2 = red_s[1][tid];
        pws[(size_t)(n * DD + d0 + tid) * SLICES + sl] =
            make_float2(a.x + c2.x, a.y + c2.y);
    }
}

// K2: merge the 8 slice partials per (n,d) row in FIXED order (deterministic),
// divide, broadcast over k with coalesced writes.
__global__ __launch_bounds__(512) void netvlad_finalize(
    const float2* __restrict__ pws, float* __restrict__ out)
{
    const int d  = threadIdx.x;
    const int n  = blockIdx.x >> 3;
    const int ks = (blockIdx.x & 7) * 8;
    float s = 0.f, ws = 0.f;
    #pragma unroll
    for (int i = 0; i < SLICES; ++i) {
        float2 v = pws[(size_t)(n * DD + d) * SLICES + i];
        s  += v.x;
        ws += v.y;
    }
    float g = ws / s;
    #pragma unroll
    for (int i = 0; i < 8; ++i)
        out[(size_t)n * KK * DD + (size_t)(ks + i) * DD + d] = g;  // coalesced
}

extern "C" void kernel_launch(void* const* d_in, const int* in_sizes, int n_in,
                              void* d_out, int out_size, void* d_ws, size_t ws_size,
                              hipStream_t stream) {
    const float* x = (const float*)d_in[0];   // (4,128,28,28)
    const float* w = (const float*)d_in[1];   // (512,128)
    const float* b = (const float*)d_in[2];   // (512,)
    // d_in[3] = centroids (64,512): provably unused — softmax over the spatial
    // axis is invariant to the per-(k,d) constant shift, so vlad[n,k,d] is
    // identical for all k.
    float2* pws = (float2*)d_ws;              // 4*512*8 float2 = 128 KB
    float* out  = (float*)d_out;              // (4,64,512) fp32

    netvlad_gemm_partial<<<NB * (DD / TD) * SLICES, BLK, 0, stream>>>(x, w, b, pws);
    netvlad_finalize<<<32, 512, 0, stream>>>(pws, out);
}

// Round 17
// 18.913 us; speedup vs baseline: 168.2085x; 1.2149x over previous
//
#include <hip/hip_runtime.h>
#include <math.h>

#define NB 4
#define CC 128
#define HW 784        // 28*28
#define KK 64
#define DD 512
#define TD 8          // d-rows per block
#define CH 64         // channels per c-half
#define NPAIR 392     // pixel pairs (784/2)
#define HTH 448       // threads per c-half — WAVE-ALIGNED (7 waves)
#define BLK 896       // 14 waves

typedef __attribute__((ext_vector_type(16))) float f32x16;

// R11 structure, but the weight path moves from LDS-broadcast ds_read_b128
// (the measured binder: broadcast b128 still costs ~12cyc of the CU's 85B/cyc
// LDS return pipe -> 1664 instr/CU = ~8.3us; model fits R4/R11/R13/R16) to
// inline-asm s_load_dwordx16 into SGPRs (scalar cache, lgkmcnt). Weight rows
// are contiguous in w[d][c], so each (d-row-pair, 16c-chunk) is two 64B
// scalar loads. v_fmac_f32 consumes the SGPR operand directly.
// c-half boundary moved to tid=448 so `ch` is wave-uniform (s_load requires
// a wave-uniform address; pinned via readfirstlane).
//   - thread = (pixel-pair, c-half); halves combined once through LDS
//   - feat = (dotL+dotH)*rinv + bias -> feat_s; waves 0..7 row-softmax
//   - vlad[n,k,d] k-independent (softmax shift-invariance) -> broadcast write
__global__ __launch_bounds__(BLK) void netvlad_fused_kernel(
    const float* __restrict__ x, const float* __restrict__ w,
    const float* __restrict__ b, float* __restrict__ out)
{
    __shared__ float feat_s[TD][HW];     // 25 KB
    __shared__ float sq_s[HW];           // 3.1 KB
    __shared__ float g_s[TD];

    const int tid = threadIdx.x;
    const int n  = blockIdx.x >> 6;
    const int d0 = (blockIdx.x & 63) * TD;

    const int  ch  = (tid >= HTH) ? 1 : 0;      // uniform per wave (448 = 7 waves)
    const int  qr  = tid - ch * HTH;            // 0..447
    const bool act = qr < NPAIR;
    const int  q   = act ? qr : (NPAIR - 1);    // clamp keeps loads in-bounds
    const int  p   = 2 * q;
    const int  cbu = __builtin_amdgcn_readfirstlane(ch * CH);  // SGPR-uniform

    const float* xp = x + (size_t)n * CC * HW + (size_t)cbu * HW + p;
    const float* wb = w + (size_t)d0 * CC + cbu;   // uniform: row d0, this half

    float acc0[TD], acc1[TD];
    #pragma unroll
    for (int j = 0; j < TD; ++j) { acc0[j] = 0.f; acc1[j] = 0.f; }
    float sq0 = 0.f, sq1 = 0.f;

    #pragma unroll
    for (int ck = 0; ck < CH; ck += 16) {
        float2 xv[16];
        #pragma unroll
        for (int u = 0; u < 16; ++u)
            xv[u] = *(const float2*)&xp[(size_t)(ck + u) * HW];  // coalesced 8B
        #pragma unroll
        for (int u = 0; u < 16; ++u) {
            sq0 = fmaf(xv[u].x, xv[u].x, sq0);
            sq1 = fmaf(xv[u].y, xv[u].y, sq1);
        }
        #pragma unroll
        for (int jp = 0; jp < TD; jp += 2) {
            f32x16 w0, w1;
            const float* a0 = wb + (size_t)jp * CC + ck;   // wave-uniform addr
            const float* a1 = a0 + CC;
            asm volatile("s_load_dwordx16 %0, %2, 0x0\n\t"
                         "s_load_dwordx16 %1, %3, 0x0\n\t"
                         "s_waitcnt lgkmcnt(0)"
                         : "=s"(w0), "=s"(w1)
                         : "s"(a0), "s"(a1));
            #pragma unroll
            for (int u = 0; u < 16; ++u) {
                acc0[jp]     = fmaf(w0[u], xv[u].x, acc0[jp]);     // SGPR src
                acc1[jp]     = fmaf(w0[u], xv[u].y, acc1[jp]);
                acc0[jp + 1] = fmaf(w1[u], xv[u].x, acc0[jp + 1]);
                acc1[jp + 1] = fmaf(w1[u], xv[u].y, acc1[jp + 1]);
            }
        }
    }

    // combine the two c-halves through LDS (one-time)
    if (act && ch == 0) {
        sq_s[p] = sq0;  sq_s[p + 1] = sq1;
        #pragma unroll
        for (int j = 0; j < TD; ++j) {
            feat_s[j][p]     = acc0[j];
            feat_s[j][p + 1] = acc1[j];
        }
    }
    __syncthreads();
    if (act && ch == 1) {
        float r0 = 1.0f / fmaxf(sqrtf(sq_s[p] + sq0), 1e-12f);
        float r1 = 1.0f / fmaxf(sqrtf(sq_s[p + 1] + sq1), 1e-12f);
        #pragma unroll
        for (int j = 0; j < TD; ++j) {
            float bj = b[d0 + j];
            feat_s[j][p]     = fmaf(feat_s[j][p]     + acc0[j], r0, bj);
            feat_s[j][p + 1] = fmaf(feat_s[j][p + 1] + acc1[j], r1, bj);
        }
    }
    __syncthreads();

    // Per-row softmax-weighted mean over P=784; wave j (j<8) handles row j.
    const int lane = tid & 63;
    const int wave = tid >> 6;
    if (wave < TD) {
        const int j = wave;
        float m = -INFINITY;
        for (int u = lane; u < HW; u += 64) m = fmaxf(m, feat_s[j][u]);
        #pragma unroll
        for (int off = 32; off; off >>= 1) m = fmaxf(m, __shfl_xor(m, off, 64));
        float s = 0.f, ws = 0.f;
        for (int u = lane; u < HW; u += 64) {
            float f = feat_s[j][u];
            float e = __expf(f - m);
            s += e;
            ws = fmaf(e, f, ws);
        }
        #pragma unroll
        for (int off = 32; off; off >>= 1) {
            s  += __shfl_xor(s, off, 64);
            ws += __shfl_xor(ws, off, 64);
        }
        if (lane == 0) g_s[j] = ws / s;
    }
    __syncthreads();

    // Broadcast across k with a coalesced write: block owns out[n, :, d0:d0+8]
    if (tid < KK * TD) {
        int k = tid >> 3, j = tid & 7;
        out[(size_t)n * KK * DD + (size_t)k * DD + d0 + j] = g_s[j];
    }
}

extern "C" void kernel_launch(void* const* d_in, const int* in_sizes, int n_in,
                              void* d_out, int out_size, void* d_ws, size_t ws_size,
                              hipStream_t stream) {
    const float* x = (const float*)d_in[0];   // (4,128,28,28)
    const float* w = (const float*)d_in[1];   // (512,128)
    const float* b = (const float*)d_in[2];   // (512,)
    // d_in[3] = centroids (64,512): provably unused — softmax over the spatial
    // axis is invariant to the per-(k,d) constant shift, so vlad[n,k,d] is
    // identical for all k.
    float* out = (float*)d_out;               // (4,64,512) fp32

    netvlad_fused_kernel<<<NB * (DD / TD), BLK, 0, stream>>>(x, w, b, out);
}

// Round 18
// 17.073 us; speedup vs baseline: 186.3387x; 1.1078x over previous
//
#include <hip/hip_runtime.h>
#include <math.h>

#define NB 4
#define CC 128
#define HW 784        // 28*28
#define KK 64
#define DD 512
#define TD 8          // d-rows per block
#define CH 64         // channels per c-half
#define NPAIR 392     // pixel pairs (784/2)
#define HTH 416       // threads per c-half (392 active + pad)
#define BLK 832       // 13 waves

typedef __attribute__((ext_vector_type(2))) float f32x2;

// R11 structure (best: 17.0us) with the FMA body moved to packed fp32
// (v_pk_fma_f32, VOP3P): one instruction computes both pixels of the pair.
// Theory: kernel is VALU-ISSUE-bound (all structural variants with identical
// chip-wide instruction counts land at 17-19us; only instruction count and
// traffic ever moved the time). Packed FMA halves the dominant instruction
// class: per channel per thread = 1 global load + 4 ds_read_b64 + 9 pk_fma
// (~14 issue slots vs R11's ~22).
//   - thread = (pixel-pair, c-half); halves combined once through LDS
//   - weight rows pair via op_sel: even row broadcasts pair.lo, odd pair.hi
//   - feat = (dot)*rinv + bias -> LDS; waves 0..7 row-softmax over P=784
//   - vlad[n,k,d] k-independent (softmax shift-invariance) -> broadcast write
__global__ __launch_bounds__(BLK) void netvlad_fused_kernel(
    const float* __restrict__ x, const float* __restrict__ w,
    const float* __restrict__ b, float* __restrict__ out)
{
    __shared__ float w_s[CC][TD];        // 4 KB, transposed [c][j]
    __shared__ float feat_s[TD][HW];     // 25 KB
    __shared__ float sq_s[HW];           // 3.1 KB
    __shared__ float g_s[TD];

    const int tid = threadIdx.x;
    const int n  = blockIdx.x >> 6;
    const int d0 = (blockIdx.x & 63) * TD;

    // stage the 8x128 weight tile transposed (one-time, 4 KB)
    for (int i = tid; i < CC * TD; i += BLK) {
        int c = i >> 3, j = i & 7;
        w_s[c][j] = w[(size_t)(d0 + j) * CC + c];
    }

    const int  ch  = (tid >= HTH) ? 1 : 0;
    const int  qr  = tid - ch * HTH;      // 0..415
    const bool act = qr < NPAIR;
    const int  q   = act ? qr : (NPAIR - 1);   // clamp keeps loads in-bounds
    const int  p   = 2 * q;
    const int  cb  = ch * CH;

    __syncthreads();

    const float* xp = x + (size_t)n * CC * HW + (size_t)cb * HW + p;

    f32x2 acc2[TD];
    #pragma unroll
    for (int j = 0; j < TD; ++j) acc2[j] = (f32x2)(0.f);
    f32x2 sq2 = (f32x2)(0.f);

    // 8-deep load batches; packed-FMA consume (both pixels per instruction)
    for (int cc = 0; cc < CH; cc += 8) {
        f32x2 xv[8];
        #pragma unroll
        for (int u = 0; u < 8; ++u)
            xv[u] = *(const f32x2*)&xp[(size_t)(cc + u) * HW];   // 8B coalesced
        #pragma unroll
        for (int u = 0; u < 8; ++u) {
            const int c = cb + cc + u;
            f32x2 w01 = *(const f32x2*)&w_s[c][0];   // rows 0,1 (ds_read_b64)
            f32x2 w23 = *(const f32x2*)&w_s[c][2];
            f32x2 w45 = *(const f32x2*)&w_s[c][4];
            f32x2 w67 = *(const f32x2*)&w_s[c][6];
            // sumsq: plain packed fma
            asm("v_pk_fma_f32 %0, %1, %1, %0"
                : "+v"(sq2) : "v"(xv[u]));
            // even rows: broadcast w-pair LO half to both lanes of the pair
            asm("v_pk_fma_f32 %0, %1, %2, %0 op_sel:[0,0,0] op_sel_hi:[1,0,1]"
                : "+v"(acc2[0]) : "v"(xv[u]), "v"(w01));
            asm("v_pk_fma_f32 %0, %1, %2, %0 op_sel:[0,1,0] op_sel_hi:[1,1,1]"
                : "+v"(acc2[1]) : "v"(xv[u]), "v"(w01));
            asm("v_pk_fma_f32 %0, %1, %2, %0 op_sel:[0,0,0] op_sel_hi:[1,0,1]"
                : "+v"(acc2[2]) : "v"(xv[u]), "v"(w23));
            asm("v_pk_fma_f32 %0, %1, %2, %0 op_sel:[0,1,0] op_sel_hi:[1,1,1]"
                : "+v"(acc2[3]) : "v"(xv[u]), "v"(w23));
            asm("v_pk_fma_f32 %0, %1, %2, %0 op_sel:[0,0,0] op_sel_hi:[1,0,1]"
                : "+v"(acc2[4]) : "v"(xv[u]), "v"(w45));
            asm("v_pk_fma_f32 %0, %1, %2, %0 op_sel:[0,1,0] op_sel_hi:[1,1,1]"
                : "+v"(acc2[5]) : "v"(xv[u]), "v"(w45));
            asm("v_pk_fma_f32 %0, %1, %2, %0 op_sel:[0,0,0] op_sel_hi:[1,0,1]"
                : "+v"(acc2[6]) : "v"(xv[u]), "v"(w67));
            asm("v_pk_fma_f32 %0, %1, %2, %0 op_sel:[0,1,0] op_sel_hi:[1,1,1]"
                : "+v"(acc2[7]) : "v"(xv[u]), "v"(w67));
        }
    }

    // combine the two c-halves through LDS (one-time, packed writes)
    if (act && ch == 0) {
        *(f32x2*)&sq_s[p] = sq2;
        #pragma unroll
        for (int j = 0; j < TD; ++j)
            *(f32x2*)&feat_s[j][p] = acc2[j];
    }
    __syncthreads();
    if (act && ch == 1) {
        f32x2 sqt = *(const f32x2*)&sq_s[p];
        float r0 = 1.0f / fmaxf(sqrtf(sqt.x + sq2.x), 1e-12f);
        float r1 = 1.0f / fmaxf(sqrtf(sqt.y + sq2.y), 1e-12f);
        #pragma unroll
        for (int j = 0; j < TD; ++j) {
            float bj = b[d0 + j];
            f32x2 f = *(const f32x2*)&feat_s[j][p];
            f.x = fmaf(f.x + acc2[j].x, r0, bj);
            f.y = fmaf(f.y + acc2[j].y, r1, bj);
            *(f32x2*)&feat_s[j][p] = f;
        }
    }
    __syncthreads();

    // Per-row softmax-weighted mean over P=784; wave j (j<8) handles row j.
    const int lane = tid & 63;
    const int wave = tid >> 6;
    if (wave < TD) {
        const int j = wave;
        float m = -INFINITY;
        for (int u = lane; u < HW; u += 64) m = fmaxf(m, feat_s[j][u]);
        #pragma unroll
        for (int off = 32; off; off >>= 1) m = fmaxf(m, __shfl_xor(m, off, 64));
        float s = 0.f, ws = 0.f;
        for (int u = lane; u < HW; u += 64) {
            float f = feat_s[j][u];
            float e = __expf(f - m);
            s += e;
            ws = fmaf(e, f, ws);
        }
        #pragma unroll
        for (int off = 32; off; off >>= 1) {
            s  += __shfl_xor(s, off, 64);
            ws += __shfl_xor(ws, off, 64);
        }
        if (lane == 0) g_s[j] = ws / s;
    }
    __syncthreads();

    // Broadcast across k with a coalesced write: block owns out[n, :, d0:d0+8]
    if (tid < KK * TD) {
        int k = tid >> 3, j = tid & 7;
        out[(size_t)n * KK * DD + (size_t)k * DD + d0 + j] = g_s[j];
    }
}

extern "C" void kernel_launch(void* const* d_in, const int* in_sizes, int n_in,
                              void* d_out, int out_size, void* d_ws, size_t ws_size,
                              hipStream_t stream) {
    const float* x = (const float*)d_in[0];   // (4,128,28,28)
    const float* w = (const float*)d_in[1];   // (512,128)
    const float* b = (const float*)d_in[2];   // (512,)
    // d_in[3] = centroids (64,512): provably unused — softmax over the spatial
    // axis is invariant to the per-(k,d) constant shift, so vlad[n,k,d] is
    // identical for all k.
    float* out = (float*)d_out;               // (4,64,512) fp32

    netvlad_fused_kernel<<<NB * (DD / TD), BLK, 0, stream>>>(x, w, b, out);
}